// Round 18
// baseline (129.140 us; speedup 1.0000x reference)
//
#include <hip/hip_runtime.h>
#include <hip/hip_bf16.h>

// Shapes: x:(16,32,128) mask:(16,128) w1:(256,66) b1:(256) w2:(128,256) b2:(128) pool_w:(128,21)
// L=128, L2=16384, dim=256, out_c=128. Output (16,128) f32.

#define NB 16
#define CIN 33
#define DIM 256
#define LEN 128
#define OC 128
#define L2 16384

typedef short bf16x8 __attribute__((ext_vector_type(8)));
typedef float f32x4 __attribute__((ext_vector_type(4)));

__device__ __forceinline__ unsigned short f32_to_bf16_rne(float f) {
    unsigned u = __float_as_uint(f);
    unsigned rb = ((u >> 16) & 1u) + 0x7FFFu;
    return (unsigned short)((u + rb) >> 16);
}
__device__ __forceinline__ float bf16_to_f32(unsigned short b) {
    return __uint_as_float(((unsigned)b) << 16);
}
// two f32 -> packed bf16 pair (v_cvt_pk_bf16_f32), RNE
__device__ __forceinline__ unsigned pk_bf16(float a, float b) {
    __hip_bfloat162 p = __float22bfloat162_rn(make_float2(a, b));
    unsigned w;
    __builtin_memcpy(&w, &p, 4);
    return w;
}

// ---------------- kernel A: ha/hb = w1a/w1b @ xm, with b1 folded in (half each) ----------------
__global__ __launch_bounds__(128) void kA(const float* __restrict__ x,
                                          const float* __restrict__ mask,
                                          const float* __restrict__ w1,
                                          const float* __restrict__ b1,
                                          float* __restrict__ ha,
                                          float* __restrict__ hb) {
    int d = blockIdx.x;
    int n = blockIdx.y;
    int l = threadIdx.x;
    const float* w1r = w1 + d * (2 * CIN);
    float a = 0.f, b = 0.f;
#pragma unroll
    for (int c = 0; c < CIN; ++c) {
        float xv = (c < 32) ? x[((size_t)n * 32 + c) * LEN + l] : mask[(size_t)n * LEN + l];
        a = fmaf(w1r[c], xv, a);
        b = fmaf(w1r[CIN + c], xv, b);
    }
    float hb1 = 0.5f * b1[d];
    ha[((size_t)n * DIM + d) * LEN + l] = a + hb1;
    hb[((size_t)n * DIM + d) * LEN + l] = b + hb1;
}

// ---------------- kernel W: w2 -> bf16 ----------------
__global__ __launch_bounds__(256) void kW(const float* __restrict__ w2,
                                          unsigned short* __restrict__ w2h) {
    int idx = blockIdx.x * 256 + threadIdx.x;   // 32768 total
    w2h[idx] = f32_to_bf16_rne(w2[idx]);
}

// ---------------- kernel B: MFMA GEMM, bf16 A (from global), bf16 B ----------------
#define ROWP 40
__global__ __launch_bounds__(256) void kB(const float* __restrict__ ha,
                                          const float* __restrict__ hb,
                                          const unsigned short* __restrict__ w2h,
                                          const float* __restrict__ b2,
                                          unsigned short* __restrict__ y,
                                          int nbase) {
    __shared__ unsigned short Bh[128 * ROWP];
    __shared__ float ha_s[DIM];
    int i0 = blockIdx.x;
    int zloc = blockIdx.y;
    int n = nbase + zloc;
    int tid = threadIdx.x;
    int wv = tid >> 6, l = tid & 63;
    int g = l >> 4, lr = l & 15;

    if (tid < DIM) ha_s[tid] = ha[((size_t)n * DIM + tid) * LEN + i0];

    f32x4 acc[2][8];
#pragma unroll
    for (int mt = 0; mt < 2; ++mt) {
        float bv[4];
#pragma unroll
        for (int r = 0; r < 4; ++r) bv[r] = b2[(wv * 2 + mt) * 16 + g * 4 + r];
#pragma unroll
        for (int nt = 0; nt < 8; ++nt)
#pragma unroll
            for (int r = 0; r < 4; ++r) acc[mt][nt][r] = bv[r];
    }

    const float* hbN = hb + (size_t)n * DIM * LEN;
    int j = tid & 127, kh = tid >> 7;
    __syncthreads();

    for (int d0 = 0; d0 < DIM; d0 += 32) {
        {
            union { unsigned w[8]; uint4 q[2]; } pkv;
#pragma unroll
            for (int kk = 0; kk < 16; kk += 2) {
                int d = d0 + kh * 16 + kk;
                float h0 = fmaxf(ha_s[d] + hbN[(size_t)d * LEN + j], 0.f);
                float h1 = fmaxf(ha_s[d + 1] + hbN[(size_t)(d + 1) * LEN + j], 0.f);
                pkv.w[kk >> 1] = pk_bf16(h0, h1);
            }
            *(uint4*)&Bh[j * ROWP + kh * 16] = pkv.q[0];
            *(uint4*)&Bh[j * ROWP + kh * 16 + 8] = pkv.q[1];
        }
        __syncthreads();

        bf16x8 ah[2];
#pragma unroll
        for (int mt = 0; mt < 2; ++mt) {
            int row = (wv * 2 + mt) * 16 + lr;
            ah[mt] = *(const bf16x8*)&w2h[(size_t)row * DIM + d0 + g * 8];
        }
#pragma unroll
        for (int nt = 0; nt < 8; ++nt) {
            int brow = nt * 16 + lr;
            bf16x8 bh = *(bf16x8*)&Bh[brow * ROWP + g * 8];
#pragma unroll
            for (int mt = 0; mt < 2; ++mt)
                acc[mt][nt] = __builtin_amdgcn_mfma_f32_16x16x32_bf16(ah[mt], bh, acc[mt][nt], 0, 0, 0);
        }
        __syncthreads();
    }

#pragma unroll
    for (int mt = 0; mt < 2; ++mt)
#pragma unroll
        for (int nt = 0; nt < 8; ++nt)
#pragma unroll
            for (int r = 0; r < 4; ++r) {
                int o = (wv * 2 + mt) * 16 + g * 4 + r;
                int col = nt * 16 + lr;
                y[((size_t)zloc * OC + o) * L2 + (size_t)i0 * LEN + col] =
                    f32_to_bf16_rne(acc[mt][nt][r]);
            }
}

// ---------------- kernel C: rank-slot histogram, wave-parity REPLICATED counters ----------------
// bin = k16>>2 (16384 bins, 4 codes). Logical word w = bin>>1 packs (bin 2w, bin 2w+1) as u16
// halves. TWO replicas interleaved: physical p = (w<<1) | (wave&1) -> even waves hit even
// words, odd waves odd words (adjacent banks). Halves per-replica contention; replicas of a
// hot word on different banks. Values stay exact (per-element phase 4); within-4-code-bin
// arrival-order ranking adds ~1e-8/elem. Segment order: bin asc; within bin replica0, replica1.
__device__ __forceinline__ unsigned swz(unsigned w) { return w ^ ((w >> 2) & 0xCu); }

__global__ __launch_bounds__(1024, 8) void kC(const unsigned short* __restrict__ y,
                                              const float* __restrict__ pw,
                                              float* __restrict__ out,
                                              int nbase) {
    extern __shared__ unsigned hist[];   // 16384 counts + 16 wave totals + 22 pwT
    int row = blockIdx.x;
    int och = row & (OC - 1);
    int n = nbase + (row >> 7);
    int t = threadIdx.x;
    int lane = t & 63, wv = t >> 6;
    unsigned rpar = wv & 1;
    const unsigned short* yr = y + (size_t)row * L2;
    const float* pwo = pw + och * 21;
    float* pwT = (float*)&hist[16384 + 16];
    int tsw = (t & 3) << 2;              // quad swizzle offset for this thread's block

    // 1. zero own 16 words + stage pw table (padded: pwT[21] = pwo[20])
#pragma unroll
    for (int q = 0; q < 4; ++q)
        *(uint4*)&hist[t * 16 + ((q << 2) ^ tsw)] = make_uint4(0, 0, 0, 0);
    if (t < 21) pwT[t] = pwo[t];
    if (t == 21) pwT[21] = pwo[20];
    __syncthreads();

    // 2. histogram into own replica; save intra-(bin,replica) offsets from atomic returns
    unsigned off16[8];
    {
        union { uint4 q[2]; unsigned short u[16]; } ld;
        ld.q[0] = *(const uint4*)&yr[t * 16];
        ld.q[1] = *(const uint4*)&yr[t * 16 + 8];
#pragma unroll
        for (int e = 0; e < 16; ++e) {
            unsigned u = ld.u[e];
            unsigned k16 = u ^ ((u & 0x8000u) ? 0xFFFFu : 0x8000u);
            unsigned bin = k16 >> 2;
            unsigned h = bin & 1;
            unsigned p = (bin & ~1u) | rpar;
            unsigned old = atomicAdd(&hist[swz(p)], h ? 0x10000u : 1u);
            unsigned myoff = h ? (old >> 16) : (old & 0xFFFFu);
            if (e & 1) off16[e >> 1] |= myoff << 16;
            else       off16[e >> 1] = myoff;
        }
    }
    __syncthreads();

    // 3a. own total (16 physical words = bins [16t,16t+16) x both replicas)
    int Ti = 0;
#pragma unroll
    for (int q = 0; q < 4; ++q) {
        uint4 v4 = *(const uint4*)&hist[t * 16 + ((q << 2) ^ tsw)];
        Ti += (int)(v4.x & 0xFFFFu) + (int)(v4.x >> 16);
        Ti += (int)(v4.y & 0xFFFFu) + (int)(v4.y >> 16);
        Ti += (int)(v4.z & 0xFFFFu) + (int)(v4.z >> 16);
        Ti += (int)(v4.w & 0xFFFFu) + (int)(v4.w >> 16);
    }
    int incl = Ti;
#pragma unroll
    for (int d = 1; d < 64; d <<= 1) {
        int u2 = __shfl_up(incl, d, 64);
        if (lane >= d) incl += u2;
    }
    if (lane == 63) hist[16384 + wv] = (unsigned)incl;   // wave totals in dedicated scratch
    __syncthreads();
    int base = 0;
#pragma unroll
    for (int k = 0; k < 16; ++k) {
        int tw = (int)hist[16384 + k];                   // broadcast read
        base += (k < wv) ? tw : 0;
    }
    int P = base + (incl - Ti);          // ascending exclusive prefix before this thread's bins

    // 3b. per quad: words (4q..4q+3) = w pairs; order bin asc, replica0 then replica1;
    //     write back descending-rank starts: start(seg) = L2 - P_incl(seg)
#pragma unroll
    for (int q = 0; q < 4; ++q) {
        unsigned* wp = &hist[t * 16 + ((q << 2) ^ tsw)];
        uint4 v4 = *(const uint4*)wp;
        unsigned r4[4] = {v4.x, v4.y, v4.z, v4.w};
        unsigned nw[4];
#pragma unroll
        for (int i = 0; i < 2; ++i) {          // w pair index within quad
            unsigned w0 = r4[2 * i], w1 = r4[2 * i + 1];   // replica0, replica1 of word w
            // bin 2w (lo halves): replica0 then replica1
            P += (int)(w0 & 0xFFFFu);
            unsigned s00 = (unsigned)(L2 - P);
            P += (int)(w1 & 0xFFFFu);
            unsigned s10 = (unsigned)(L2 - P);
            // bin 2w+1 (hi halves)
            P += (int)(w0 >> 16);
            unsigned s01 = (unsigned)(L2 - P);
            P += (int)(w1 >> 16);
            unsigned s11 = (unsigned)(L2 - P);
            nw[2 * i]     = s00 | (s01 << 16);
            nw[2 * i + 1] = s10 | (s11 << 16);
        }
        *(uint4*)wp = make_uint4(nw[0], nw[1], nw[2], nw[3]);
    }
    __syncthreads();

    // 4. re-read y (L2-hot); rank = seg start + saved offset; weight via LDS pw table
    float acc = 0.f;
    {
        union { uint4 q[2]; unsigned short u[16]; } ld;
        ld.q[0] = *(const uint4*)&yr[t * 16];
        ld.q[1] = *(const uint4*)&yr[t * 16 + 8];
#pragma unroll
        for (int e = 0; e < 16; ++e) {
            unsigned u = ld.u[e];
            unsigned k16 = u ^ ((u & 0x8000u) ? 0xFFFFu : 0x8000u);
            unsigned bin = k16 >> 2;
            unsigned h = bin & 1;
            unsigned p = (bin & ~1u) | rpar;
            unsigned w = hist[swz(p)];                   // same-word reads broadcast
            unsigned start = h ? (w >> 16) : (w & 0xFFFFu);
            unsigned myoff = (e & 1) ? (off16[e >> 1] >> 16) : (off16[e >> 1] & 0xFFFFu);
            int r = (int)(start + myoff);
            float idxf = (float)r * (20.0f / 16383.0f);  // r <= 16383 -> no clamp needed
            int idx = (int)idxf;
            float frac = idxf - (float)idx;
            float wvw = (1.0f - frac) * pwT[idx] + frac * pwT[idx + 1];
            float val = __uint_as_float(((unsigned)u) << 16);
            acc = fmaf(val, wvw, acc);
        }
    }

    // 5. reduce (scratch words reused after barrier)
#pragma unroll
    for (int d = 32; d >= 1; d >>= 1) acc += __shfl_xor(acc, d, 64);
    __syncthreads();
    if (lane == 0) ((float*)hist)[16384 + wv] = acc;
    __syncthreads();
    if (t == 0) {
        double tot = 0.0;
#pragma unroll
        for (int k = 0; k < 16; ++k) tot += (double)((const float*)hist)[16384 + k];
        out[(size_t)n * OC + och] = (float)(tot * (1.0 / (double)L2));
    }
}

extern "C" void kernel_launch(void* const* d_in, const int* in_sizes, int n_in,
                              void* d_out, int out_size, void* d_ws, size_t ws_size,
                              hipStream_t stream) {
    const float* x    = (const float*)d_in[0];
    const float* mask = (const float*)d_in[1];
    const float* w1   = (const float*)d_in[2];
    const float* b1   = (const float*)d_in[3];
    const float* w2   = (const float*)d_in[4];
    const float* b2   = (const float*)d_in[5];
    const float* pw   = (const float*)d_in[6];
    float* out = (float*)d_out;

    char* ws = (char*)d_ws;
    float* ha = (float*)ws;                                       // 2 MB
    float* hb = ha + (size_t)NB * DIM * LEN;                      // 2 MB
    unsigned short* w2h = (unsigned short*)(ws + (size_t)2 * NB * DIM * LEN * 4);   // 64 KB
    unsigned short* y = w2h + (size_t)2 * OC * DIM;               // up to 64 MB bf16

    size_t used = (size_t)2 * NB * DIM * LEN * 4 + (size_t)2 * OC * DIM * 2;
    size_t perN = (size_t)OC * L2 * 2;   // 4 MB per n (bf16)
    int nchunk = 1;
    if (ws_size > used + perN) {
        size_t c = (ws_size - used) / perN;
        nchunk = (int)(c > NB ? NB : c);
    }

    hipLaunchKernelGGL(kA, dim3(DIM, NB), dim3(128), 0, stream, x, mask, w1, b1, ha, hb);
    hipLaunchKernelGGL(kW, dim3(OC * DIM / 256), dim3(256), 0, stream, w2, w2h);
    for (int base = 0; base < NB; base += nchunk) {
        int nc = nchunk < (NB - base) ? nchunk : (NB - base);
        hipLaunchKernelGGL(kB, dim3(LEN, nc), dim3(256), 0, stream, ha, hb, w2h, b2, y, base);
        hipLaunchKernelGGL(kC, dim3(OC * nc), dim3(1024), (16384 + 16 + 22) * 4, stream, y, pw, out, base);
    }
}

// Round 19
// 125.191 us; speedup vs baseline: 1.0315x; 1.0315x over previous
//
#include <hip/hip_runtime.h>
#include <hip/hip_bf16.h>

// Shapes: x:(16,32,128) mask:(16,128) w1:(256,66) b1:(256) w2:(128,256) b2:(128) pool_w:(128,21)
// L=128, L2=16384, dim=256, out_c=128. Output (16,128) f32.

#define NB 16
#define CIN 33
#define DIM 256
#define LEN 128
#define OC 128
#define L2 16384

typedef short bf16x8 __attribute__((ext_vector_type(8)));
typedef float f32x4 __attribute__((ext_vector_type(4)));

__device__ __forceinline__ unsigned short f32_to_bf16_rne(float f) {
    unsigned u = __float_as_uint(f);
    unsigned rb = ((u >> 16) & 1u) + 0x7FFFu;
    return (unsigned short)((u + rb) >> 16);
}
__device__ __forceinline__ float bf16_to_f32(unsigned short b) {
    return __uint_as_float(((unsigned)b) << 16);
}
// two f32 -> packed bf16 pair (v_cvt_pk_bf16_f32), RNE
__device__ __forceinline__ unsigned pk_bf16(float a, float b) {
    __hip_bfloat162 p = __float22bfloat162_rn(make_float2(a, b));
    unsigned w;
    __builtin_memcpy(&w, &p, 4);
    return w;
}

// ---------------- kernel A: ha/hb = w1a/w1b @ xm, with b1 folded in (half each) ----------------
__global__ __launch_bounds__(128) void kA(const float* __restrict__ x,
                                          const float* __restrict__ mask,
                                          const float* __restrict__ w1,
                                          const float* __restrict__ b1,
                                          float* __restrict__ ha,
                                          float* __restrict__ hb) {
    int d = blockIdx.x;
    int n = blockIdx.y;
    int l = threadIdx.x;
    const float* w1r = w1 + d * (2 * CIN);
    float a = 0.f, b = 0.f;
#pragma unroll
    for (int c = 0; c < CIN; ++c) {
        float xv = (c < 32) ? x[((size_t)n * 32 + c) * LEN + l] : mask[(size_t)n * LEN + l];
        a = fmaf(w1r[c], xv, a);
        b = fmaf(w1r[CIN + c], xv, b);
    }
    float hb1 = 0.5f * b1[d];
    ha[((size_t)n * DIM + d) * LEN + l] = a + hb1;
    hb[((size_t)n * DIM + d) * LEN + l] = b + hb1;
}

// ---------------- kernel W: w2 -> bf16 ----------------
__global__ __launch_bounds__(256) void kW(const float* __restrict__ w2,
                                          unsigned short* __restrict__ w2h) {
    int idx = blockIdx.x * 256 + threadIdx.x;   // 32768 total
    w2h[idx] = f32_to_bf16_rne(w2[idx]);
}

// ---------------- kernel B: MFMA GEMM, bf16 A (global), bf16 B, double-buffered pipeline ------
// Per step: prefetch next hb chunk to regs -> MFMA on current B tile -> cvt+write next tile ->
// ONE barrier. Load latency hides under MFMA; write targets the buffer no wave reads this step;
// the end-of-step barrier protects against step-(k-1) readers of the buffer being written.
#define ROWP 40
__global__ __launch_bounds__(256) void kB(const float* __restrict__ ha,
                                          const float* __restrict__ hb,
                                          const unsigned short* __restrict__ w2h,
                                          const float* __restrict__ b2,
                                          unsigned short* __restrict__ y,
                                          int nbase) {
    __shared__ unsigned short Bh[2][128 * ROWP];
    __shared__ float ha_s[DIM];
    int i0 = blockIdx.x;
    int zloc = blockIdx.y;
    int n = nbase + zloc;
    int tid = threadIdx.x;
    int wv = tid >> 6, l = tid & 63;
    int g = l >> 4, lr = l & 15;

    if (tid < DIM) ha_s[tid] = ha[((size_t)n * DIM + tid) * LEN + i0];

    f32x4 acc[2][8];
#pragma unroll
    for (int mt = 0; mt < 2; ++mt) {
        float bv[4];
#pragma unroll
        for (int r = 0; r < 4; ++r) bv[r] = b2[(wv * 2 + mt) * 16 + g * 4 + r];
#pragma unroll
        for (int nt = 0; nt < 8; ++nt)
#pragma unroll
            for (int r = 0; r < 4; ++r) acc[mt][nt][r] = bv[r];
    }

    const float* hbN = hb + (size_t)n * DIM * LEN;
    int j = tid & 127, kh = tid >> 7;
    __syncthreads();   // ha_s ready

    // prologue: build B tile for step 0
    {
        float hv[16];
#pragma unroll
        for (int kk = 0; kk < 16; ++kk)
            hv[kk] = hbN[(size_t)(kh * 16 + kk) * LEN + j];
        union { unsigned w[8]; uint4 q[2]; } pkv;
#pragma unroll
        for (int kk = 0; kk < 16; kk += 2) {
            int d = kh * 16 + kk;
            pkv.w[kk >> 1] = pk_bf16(fmaxf(ha_s[d] + hv[kk], 0.f),
                                     fmaxf(ha_s[d + 1] + hv[kk + 1], 0.f));
        }
        *(uint4*)&Bh[0][j * ROWP + kh * 16] = pkv.q[0];
        *(uint4*)&Bh[0][j * ROWP + kh * 16 + 8] = pkv.q[1];
    }
    __syncthreads();

#pragma unroll
    for (int s = 0; s < 8; ++s) {
        int cur = s & 1;
        // ---- prefetch next step's hb chunk into registers (latency hides under MFMA) ----
        float nv[16];
        if (s < 7) {
            int dbase = (s + 1) * 32 + kh * 16;
#pragma unroll
            for (int kk = 0; kk < 16; ++kk)
                nv[kk] = hbN[(size_t)(dbase + kk) * LEN + j];
        }

        // ---- MFMA on current tile; A frags from global (L2-hot) ----
        int d0 = s * 32;
        bf16x8 ah[2];
#pragma unroll
        for (int mt = 0; mt < 2; ++mt) {
            int row = (wv * 2 + mt) * 16 + lr;
            ah[mt] = *(const bf16x8*)&w2h[(size_t)row * DIM + d0 + g * 8];
        }
#pragma unroll
        for (int nt = 0; nt < 8; ++nt) {
            int brow = nt * 16 + lr;
            bf16x8 bh = *(bf16x8*)&Bh[cur][brow * ROWP + g * 8];
#pragma unroll
            for (int mt = 0; mt < 2; ++mt)
                acc[mt][nt] = __builtin_amdgcn_mfma_f32_16x16x32_bf16(ah[mt], bh, acc[mt][nt], 0, 0, 0);
        }

        // ---- build next tile into the alternate buffer ----
        if (s < 7) {
            int dbase = (s + 1) * 32 + kh * 16;
            union { unsigned w[8]; uint4 q[2]; } pkv;
#pragma unroll
            for (int kk = 0; kk < 16; kk += 2) {
                int d = dbase + kk;
                pkv.w[kk >> 1] = pk_bf16(fmaxf(ha_s[d] + nv[kk], 0.f),
                                         fmaxf(ha_s[d + 1] + nv[kk + 1], 0.f));
            }
            *(uint4*)&Bh[cur ^ 1][j * ROWP + kh * 16] = pkv.q[0];
            *(uint4*)&Bh[cur ^ 1][j * ROWP + kh * 16 + 8] = pkv.q[1];
        }
        __syncthreads();
    }

#pragma unroll
    for (int mt = 0; mt < 2; ++mt)
#pragma unroll
        for (int nt = 0; nt < 8; ++nt)
#pragma unroll
            for (int r = 0; r < 4; ++r) {
                int o = (wv * 2 + mt) * 16 + g * 4 + r;
                int col = nt * 16 + lr;
                y[((size_t)zloc * OC + o) * L2 + (size_t)i0 * LEN + col] =
                    f32_to_bf16_rne(acc[mt][nt][r]);
            }
}

// ---------------- kernel C: rank-slot histogram pooling (R16 measured-best, 77.7 us) ----------
__device__ __forceinline__ unsigned swz(unsigned w) { return w ^ ((w >> 2) & 0xCu); }

__global__ __launch_bounds__(1024, 8) void kC(const unsigned short* __restrict__ y,
                                              const float* __restrict__ pw,
                                              float* __restrict__ out,
                                              int nbase) {
    extern __shared__ unsigned hist[];   // 16384 counts + 16 wave totals + 22 pwT
    int row = blockIdx.x;
    int och = row & (OC - 1);
    int n = nbase + (row >> 7);
    int t = threadIdx.x;
    int lane = t & 63, wv = t >> 6;
    const unsigned short* yr = y + (size_t)row * L2;
    const float* pwo = pw + och * 21;
    float* pwT = (float*)&hist[16384 + 16];
    int tsw = (t & 3) << 2;              // quad swizzle offset for this thread's block

    // 1. zero own 16 words + stage pw table (padded: pwT[21] = pwo[20])
#pragma unroll
    for (int q = 0; q < 4; ++q)
        *(uint4*)&hist[t * 16 + ((q << 2) ^ tsw)] = make_uint4(0, 0, 0, 0);
    if (t < 21) pwT[t] = pwo[t];
    if (t == 21) pwT[21] = pwo[20];
    __syncthreads();

    // 2. histogram; save intra-bin offsets from atomic returns
    unsigned off16[8];
    {
        union { uint4 q[2]; unsigned short u[16]; } ld;
        ld.q[0] = *(const uint4*)&yr[t * 16];
        ld.q[1] = *(const uint4*)&yr[t * 16 + 8];
#pragma unroll
        for (int e = 0; e < 16; ++e) {
            unsigned u = ld.u[e];
            unsigned k16 = u ^ ((u & 0x8000u) ? 0xFFFFu : 0x8000u);
            unsigned hi = (k16 >> 1) & 1;
            unsigned old = atomicAdd(&hist[swz(k16 >> 2)], hi ? 0x10000u : 1u);
            unsigned myoff = hi ? (old >> 16) : (old & 0xFFFFu);
            if (e & 1) off16[e >> 1] |= myoff << 16;
            else       off16[e >> 1] = myoff;
        }
    }
    __syncthreads();

    // 3a. own-bin total (re-read quads; no register cache)
    int Ti = 0;
#pragma unroll
    for (int q = 0; q < 4; ++q) {
        uint4 v4 = *(const uint4*)&hist[t * 16 + ((q << 2) ^ tsw)];
        Ti += (int)(v4.x & 0xFFFFu) + (int)(v4.x >> 16);
        Ti += (int)(v4.y & 0xFFFFu) + (int)(v4.y >> 16);
        Ti += (int)(v4.z & 0xFFFFu) + (int)(v4.z >> 16);
        Ti += (int)(v4.w & 0xFFFFu) + (int)(v4.w >> 16);
    }
    int incl = Ti;
#pragma unroll
    for (int d = 1; d < 64; d <<= 1) {
        int u2 = __shfl_up(incl, d, 64);
        if (lane >= d) incl += u2;
    }
    if (lane == 63) hist[16384 + wv] = (unsigned)incl;   // wave totals in dedicated scratch
    __syncthreads();
    int base = 0;
#pragma unroll
    for (int k = 0; k < 16; ++k) {
        int tw = (int)hist[16384 + k];                   // broadcast read
        base += (k < wv) ? tw : 0;
    }
    int P = base + (incl - Ti);          // ascending exclusive prefix before this thread's bins

    // 3b. re-read quads, write back per-bin descending-rank starts: start(b) = L2 - P_incl(b)
#pragma unroll
    for (int q = 0; q < 4; ++q) {
        unsigned* wp = &hist[t * 16 + ((q << 2) ^ tsw)];
        uint4 v4 = *(const uint4*)wp;
        unsigned r4[4] = {v4.x, v4.y, v4.z, v4.w};
#pragma unroll
        for (int c = 0; c < 4; ++c) {
            int clo = (int)(r4[c] & 0xFFFFu), chi = (int)(r4[c] >> 16);
            P += clo;
            unsigned slo = (unsigned)(L2 - P);
            P += chi;
            unsigned shi = (unsigned)(L2 - P);
            r4[c] = slo | (shi << 16);
        }
        *(uint4*)wp = make_uint4(r4[0], r4[1], r4[2], r4[3]);
    }
    __syncthreads();

    // 4. re-read y (L2-hot); rank = bin start + saved offset; weight via LDS pw table
    float acc = 0.f;
    {
        union { uint4 q[2]; unsigned short u[16]; } ld;
        ld.q[0] = *(const uint4*)&yr[t * 16];
        ld.q[1] = *(const uint4*)&yr[t * 16 + 8];
#pragma unroll
        for (int e = 0; e < 16; ++e) {
            unsigned u = ld.u[e];
            unsigned k16 = u ^ ((u & 0x8000u) ? 0xFFFFu : 0x8000u);
            unsigned hi = (k16 >> 1) & 1;
            unsigned w = hist[swz(k16 >> 2)];            // same-word reads broadcast
            unsigned start = hi ? (w >> 16) : (w & 0xFFFFu);
            unsigned myoff = (e & 1) ? (off16[e >> 1] >> 16) : (off16[e >> 1] & 0xFFFFu);
            int r = (int)(start + myoff);
            float posf = fminf((float)r * (1.0f / 16383.0f), 1.0f);
            float idxf = 20.0f * posf;
            int idx = (int)idxf;
            float frac = idxf - (float)idx;
            float wvw = (1.0f - frac) * pwT[idx] + frac * pwT[idx + 1];
            float val = __uint_as_float(((unsigned)u) << 16);
            acc = fmaf(val, wvw, acc);
        }
    }

    // 5. reduce (scratch words reused after barrier)
#pragma unroll
    for (int d = 32; d >= 1; d >>= 1) acc += __shfl_xor(acc, d, 64);
    __syncthreads();
    if (lane == 0) ((float*)hist)[16384 + wv] = acc;
    __syncthreads();
    if (t == 0) {
        double tot = 0.0;
#pragma unroll
        for (int k = 0; k < 16; ++k) tot += (double)((const float*)hist)[16384 + k];
        out[(size_t)n * OC + och] = (float)(tot * (1.0 / (double)L2));
    }
}

extern "C" void kernel_launch(void* const* d_in, const int* in_sizes, int n_in,
                              void* d_out, int out_size, void* d_ws, size_t ws_size,
                              hipStream_t stream) {
    const float* x    = (const float*)d_in[0];
    const float* mask = (const float*)d_in[1];
    const float* w1   = (const float*)d_in[2];
    const float* b1   = (const float*)d_in[3];
    const float* w2   = (const float*)d_in[4];
    const float* b2   = (const float*)d_in[5];
    const float* pw   = (const float*)d_in[6];
    float* out = (float*)d_out;

    char* ws = (char*)d_ws;
    float* ha = (float*)ws;                                       // 2 MB
    float* hb = ha + (size_t)NB * DIM * LEN;                      // 2 MB
    unsigned short* w2h = (unsigned short*)(ws + (size_t)2 * NB * DIM * LEN * 4);   // 64 KB
    unsigned short* y = w2h + (size_t)2 * OC * DIM;               // up to 64 MB bf16

    size_t used = (size_t)2 * NB * DIM * LEN * 4 + (size_t)2 * OC * DIM * 2;
    size_t perN = (size_t)OC * L2 * 2;   // 4 MB per n (bf16)
    int nchunk = 1;
    if (ws_size > used + perN) {
        size_t c = (ws_size - used) / perN;
        nchunk = (int)(c > NB ? NB : c);
    }

    hipLaunchKernelGGL(kA, dim3(DIM, NB), dim3(128), 0, stream, x, mask, w1, b1, ha, hb);
    hipLaunchKernelGGL(kW, dim3(OC * DIM / 256), dim3(256), 0, stream, w2, w2h);
    for (int base = 0; base < NB; base += nchunk) {
        int nc = nchunk < (NB - base) ? nchunk : (NB - base);
        hipLaunchKernelGGL(kB, dim3(LEN, nc), dim3(256), 0, stream, ha, hb, w2h, b2, y, base);
        hipLaunchKernelGGL(kC, dim3(OC * nc), dim3(1024), (16384 + 16 + 22) * 4, stream, y, pw, out, base);
    }
}

// Round 20
// 118.979 us; speedup vs baseline: 1.0854x; 1.0522x over previous
//
#include <hip/hip_runtime.h>
#include <hip/hip_bf16.h>

// Shapes: x:(16,32,128) mask:(16,128) w1:(256,66) b1:(256) w2:(128,256) b2:(128) pool_w:(128,21)
// L=128, L2=16384, dim=256, out_c=128. Output (16,128) f32.

#define NB 16
#define CIN 33
#define DIM 256
#define LEN 128
#define OC 128
#define L2 16384

typedef short bf16x8 __attribute__((ext_vector_type(8)));
typedef float f32x4 __attribute__((ext_vector_type(4)));

__device__ __forceinline__ unsigned short f32_to_bf16_rne(float f) {
    unsigned u = __float_as_uint(f);
    unsigned rb = ((u >> 16) & 1u) + 0x7FFFu;
    return (unsigned short)((u + rb) >> 16);
}
__device__ __forceinline__ float bf16_to_f32(unsigned short b) {
    return __uint_as_float(((unsigned)b) << 16);
}
// two f32 -> packed bf16 pair (v_cvt_pk_bf16_f32), RNE
__device__ __forceinline__ unsigned pk_bf16(float a, float b) {
    __hip_bfloat162 p = __float22bfloat162_rn(make_float2(a, b));
    unsigned w;
    __builtin_memcpy(&w, &p, 4);
    return w;
}

// ---------------- kernel A: ha/hb = w1a/w1b @ xm, with b1 folded in (half each) ----------------
__global__ __launch_bounds__(128) void kA(const float* __restrict__ x,
                                          const float* __restrict__ mask,
                                          const float* __restrict__ w1,
                                          const float* __restrict__ b1,
                                          float* __restrict__ ha,
                                          float* __restrict__ hb) {
    int d = blockIdx.x;
    int n = blockIdx.y;
    int l = threadIdx.x;
    const float* w1r = w1 + d * (2 * CIN);
    float a = 0.f, b = 0.f;
#pragma unroll
    for (int c = 0; c < CIN; ++c) {
        float xv = (c < 32) ? x[((size_t)n * 32 + c) * LEN + l] : mask[(size_t)n * LEN + l];
        a = fmaf(w1r[c], xv, a);
        b = fmaf(w1r[CIN + c], xv, b);
    }
    float hb1 = 0.5f * b1[d];
    ha[((size_t)n * DIM + d) * LEN + l] = a + hb1;
    hb[((size_t)n * DIM + d) * LEN + l] = b + hb1;
}

// ---------------- kernel W: w2 -> bf16 ----------------
__global__ __launch_bounds__(256) void kW(const float* __restrict__ w2,
                                          unsigned short* __restrict__ w2h) {
    int idx = blockIdx.x * 256 + threadIdx.x;   // 32768 total
    w2h[idx] = f32_to_bf16_rne(w2[idx]);
}

// ---------------- kernel B: MFMA GEMM, bf16 A (global, prefetched), bf16 B, double-buffered ----
// Per step: prefetch next hb chunk AND next A-frags to regs -> MFMA on current tile (A-frags
// already resident, no exposed L2 latency) -> cvt+write next tile -> ONE barrier.
#define ROWP 40
__global__ __launch_bounds__(256) void kB(const float* __restrict__ ha,
                                          const float* __restrict__ hb,
                                          const unsigned short* __restrict__ w2h,
                                          const float* __restrict__ b2,
                                          unsigned short* __restrict__ y,
                                          int nbase) {
    __shared__ unsigned short Bh[2][128 * ROWP];
    __shared__ float ha_s[DIM];
    int i0 = blockIdx.x;
    int zloc = blockIdx.y;
    int n = nbase + zloc;
    int tid = threadIdx.x;
    int wv = tid >> 6, l = tid & 63;
    int g = l >> 4, lr = l & 15;

    if (tid < DIM) ha_s[tid] = ha[((size_t)n * DIM + tid) * LEN + i0];

    f32x4 acc[2][8];
#pragma unroll
    for (int mt = 0; mt < 2; ++mt) {
        float bv[4];
#pragma unroll
        for (int r = 0; r < 4; ++r) bv[r] = b2[(wv * 2 + mt) * 16 + g * 4 + r];
#pragma unroll
        for (int nt = 0; nt < 8; ++nt)
#pragma unroll
            for (int r = 0; r < 4; ++r) acc[mt][nt][r] = bv[r];
    }

    const float* hbN = hb + (size_t)n * DIM * LEN;
    int j = tid & 127, kh = tid >> 7;
    // A-frag base addresses (per wave/lane, advance by 32 per step)
    const unsigned short* aptr[2];
#pragma unroll
    for (int mt = 0; mt < 2; ++mt)
        aptr[mt] = w2h + (size_t)((wv * 2 + mt) * 16 + lr) * DIM + g * 8;
    __syncthreads();   // ha_s ready

    // prologue: build B tile for step 0; prefetch A frags for step 0
    bf16x8 ahc[2];
#pragma unroll
    for (int mt = 0; mt < 2; ++mt) ahc[mt] = *(const bf16x8*)&aptr[mt][0];
    {
        float hv[16];
#pragma unroll
        for (int kk = 0; kk < 16; ++kk)
            hv[kk] = hbN[(size_t)(kh * 16 + kk) * LEN + j];
        union { unsigned w[8]; uint4 q[2]; } pkv;
#pragma unroll
        for (int kk = 0; kk < 16; kk += 2) {
            int d = kh * 16 + kk;
            pkv.w[kk >> 1] = pk_bf16(fmaxf(ha_s[d] + hv[kk], 0.f),
                                     fmaxf(ha_s[d + 1] + hv[kk + 1], 0.f));
        }
        *(uint4*)&Bh[0][j * ROWP + kh * 16] = pkv.q[0];
        *(uint4*)&Bh[0][j * ROWP + kh * 16 + 8] = pkv.q[1];
    }
    __syncthreads();

#pragma unroll
    for (int s = 0; s < 8; ++s) {
        int cur = s & 1;
        // ---- prefetch next step's hb chunk + A frags into registers ----
        float nv[16];
        bf16x8 ahn[2];
        if (s < 7) {
            int dbase = (s + 1) * 32 + kh * 16;
#pragma unroll
            for (int kk = 0; kk < 16; ++kk)
                nv[kk] = hbN[(size_t)(dbase + kk) * LEN + j];
#pragma unroll
            for (int mt = 0; mt < 2; ++mt)
                ahn[mt] = *(const bf16x8*)&aptr[mt][(s + 1) * 32];
        }

        // ---- MFMA on current tile; A frags already resident ----
#pragma unroll
        for (int nt = 0; nt < 8; ++nt) {
            int brow = nt * 16 + lr;
            bf16x8 bh = *(bf16x8*)&Bh[cur][brow * ROWP + g * 8];
#pragma unroll
            for (int mt = 0; mt < 2; ++mt)
                acc[mt][nt] = __builtin_amdgcn_mfma_f32_16x16x32_bf16(ahc[mt], bh, acc[mt][nt], 0, 0, 0);
        }

        // ---- build next tile into the alternate buffer; rotate A frags ----
        if (s < 7) {
            int dbase = (s + 1) * 32 + kh * 16;
            union { unsigned w[8]; uint4 q[2]; } pkv;
#pragma unroll
            for (int kk = 0; kk < 16; kk += 2) {
                int d = dbase + kk;
                pkv.w[kk >> 1] = pk_bf16(fmaxf(ha_s[d] + nv[kk], 0.f),
                                         fmaxf(ha_s[d + 1] + nv[kk + 1], 0.f));
            }
            *(uint4*)&Bh[cur ^ 1][j * ROWP + kh * 16] = pkv.q[0];
            *(uint4*)&Bh[cur ^ 1][j * ROWP + kh * 16 + 8] = pkv.q[1];
            ahc[0] = ahn[0];
            ahc[1] = ahn[1];
        }
        __syncthreads();
    }

#pragma unroll
    for (int mt = 0; mt < 2; ++mt)
#pragma unroll
        for (int nt = 0; nt < 8; ++nt)
#pragma unroll
            for (int r = 0; r < 4; ++r) {
                int o = (wv * 2 + mt) * 16 + g * 4 + r;
                int col = nt * 16 + lr;
                y[((size_t)zloc * OC + o) * L2 + (size_t)i0 * LEN + col] =
                    f32_to_bf16_rne(acc[mt][nt][r]);
            }
}

// ---------------- kernel C: rank-slot histogram pooling (R16/R18 measured-best, 77.5 us) ------
__device__ __forceinline__ unsigned swz(unsigned w) { return w ^ ((w >> 2) & 0xCu); }

__global__ __launch_bounds__(1024, 8) void kC(const unsigned short* __restrict__ y,
                                              const float* __restrict__ pw,
                                              float* __restrict__ out,
                                              int nbase) {
    extern __shared__ unsigned hist[];   // 16384 counts + 16 wave totals + 22 pwT
    int row = blockIdx.x;
    int och = row & (OC - 1);
    int n = nbase + (row >> 7);
    int t = threadIdx.x;
    int lane = t & 63, wv = t >> 6;
    const unsigned short* yr = y + (size_t)row * L2;
    const float* pwo = pw + och * 21;
    float* pwT = (float*)&hist[16384 + 16];
    int tsw = (t & 3) << 2;              // quad swizzle offset for this thread's block

    // 1. zero own 16 words + stage pw table (padded: pwT[21] = pwo[20])
#pragma unroll
    for (int q = 0; q < 4; ++q)
        *(uint4*)&hist[t * 16 + ((q << 2) ^ tsw)] = make_uint4(0, 0, 0, 0);
    if (t < 21) pwT[t] = pwo[t];
    if (t == 21) pwT[21] = pwo[20];
    __syncthreads();

    // 2. histogram; save intra-bin offsets from atomic returns
    unsigned off16[8];
    {
        union { uint4 q[2]; unsigned short u[16]; } ld;
        ld.q[0] = *(const uint4*)&yr[t * 16];
        ld.q[1] = *(const uint4*)&yr[t * 16 + 8];
#pragma unroll
        for (int e = 0; e < 16; ++e) {
            unsigned u = ld.u[e];
            unsigned k16 = u ^ ((u & 0x8000u) ? 0xFFFFu : 0x8000u);
            unsigned hi = (k16 >> 1) & 1;
            unsigned old = atomicAdd(&hist[swz(k16 >> 2)], hi ? 0x10000u : 1u);
            unsigned myoff = hi ? (old >> 16) : (old & 0xFFFFu);
            if (e & 1) off16[e >> 1] |= myoff << 16;
            else       off16[e >> 1] = myoff;
        }
    }
    __syncthreads();

    // 3a. own-bin total (re-read quads; no register cache)
    int Ti = 0;
#pragma unroll
    for (int q = 0; q < 4; ++q) {
        uint4 v4 = *(const uint4*)&hist[t * 16 + ((q << 2) ^ tsw)];
        Ti += (int)(v4.x & 0xFFFFu) + (int)(v4.x >> 16);
        Ti += (int)(v4.y & 0xFFFFu) + (int)(v4.y >> 16);
        Ti += (int)(v4.z & 0xFFFFu) + (int)(v4.z >> 16);
        Ti += (int)(v4.w & 0xFFFFu) + (int)(v4.w >> 16);
    }
    int incl = Ti;
#pragma unroll
    for (int d = 1; d < 64; d <<= 1) {
        int u2 = __shfl_up(incl, d, 64);
        if (lane >= d) incl += u2;
    }
    if (lane == 63) hist[16384 + wv] = (unsigned)incl;   // wave totals in dedicated scratch
    __syncthreads();
    int base = 0;
#pragma unroll
    for (int k = 0; k < 16; ++k) {
        int tw = (int)hist[16384 + k];                   // broadcast read
        base += (k < wv) ? tw : 0;
    }
    int P = base + (incl - Ti);          // ascending exclusive prefix before this thread's bins

    // 3b. re-read quads, write back per-bin descending-rank starts: start(b) = L2 - P_incl(b)
#pragma unroll
    for (int q = 0; q < 4; ++q) {
        unsigned* wp = &hist[t * 16 + ((q << 2) ^ tsw)];
        uint4 v4 = *(const uint4*)wp;
        unsigned r4[4] = {v4.x, v4.y, v4.z, v4.w};
#pragma unroll
        for (int c = 0; c < 4; ++c) {
            int clo = (int)(r4[c] & 0xFFFFu), chi = (int)(r4[c] >> 16);
            P += clo;
            unsigned slo = (unsigned)(L2 - P);
            P += chi;
            unsigned shi = (unsigned)(L2 - P);
            r4[c] = slo | (shi << 16);
        }
        *(uint4*)wp = make_uint4(r4[0], r4[1], r4[2], r4[3]);
    }
    __syncthreads();

    // 4. re-read y (L2-hot); rank = bin start + saved offset; weight via LDS pw table
    float acc = 0.f;
    {
        union { uint4 q[2]; unsigned short u[16]; } ld;
        ld.q[0] = *(const uint4*)&yr[t * 16];
        ld.q[1] = *(const uint4*)&yr[t * 16 + 8];
#pragma unroll
        for (int e = 0; e < 16; ++e) {
            unsigned u = ld.u[e];
            unsigned k16 = u ^ ((u & 0x8000u) ? 0xFFFFu : 0x8000u);
            unsigned hi = (k16 >> 1) & 1;
            unsigned w = hist[swz(k16 >> 2)];            // same-word reads broadcast
            unsigned start = hi ? (w >> 16) : (w & 0xFFFFu);
            unsigned myoff = (e & 1) ? (off16[e >> 1] >> 16) : (off16[e >> 1] & 0xFFFFu);
            int r = (int)(start + myoff);
            float posf = fminf((float)r * (1.0f / 16383.0f), 1.0f);
            float idxf = 20.0f * posf;
            int idx = (int)idxf;
            float frac = idxf - (float)idx;
            float wvw = (1.0f - frac) * pwT[idx] + frac * pwT[idx + 1];
            float val = __uint_as_float(((unsigned)u) << 16);
            acc = fmaf(val, wvw, acc);
        }
    }

    // 5. reduce (scratch words reused after barrier)
#pragma unroll
    for (int d = 32; d >= 1; d >>= 1) acc += __shfl_xor(acc, d, 64);
    __syncthreads();
    if (lane == 0) ((float*)hist)[16384 + wv] = acc;
    __syncthreads();
    if (t == 0) {
        double tot = 0.0;
#pragma unroll
        for (int k = 0; k < 16; ++k) tot += (double)((const float*)hist)[16384 + k];
        out[(size_t)n * OC + och] = (float)(tot * (1.0 / (double)L2));
    }
}

extern "C" void kernel_launch(void* const* d_in, const int* in_sizes, int n_in,
                              void* d_out, int out_size, void* d_ws, size_t ws_size,
                              hipStream_t stream) {
    const float* x    = (const float*)d_in[0];
    const float* mask = (const float*)d_in[1];
    const float* w1   = (const float*)d_in[2];
    const float* b1   = (const float*)d_in[3];
    const float* w2   = (const float*)d_in[4];
    const float* b2   = (const float*)d_in[5];
    const float* pw   = (const float*)d_in[6];
    float* out = (float*)d_out;

    char* ws = (char*)d_ws;
    float* ha = (float*)ws;                                       // 2 MB
    float* hb = ha + (size_t)NB * DIM * LEN;                      // 2 MB
    unsigned short* w2h = (unsigned short*)(ws + (size_t)2 * NB * DIM * LEN * 4);   // 64 KB
    unsigned short* y = w2h + (size_t)2 * OC * DIM;               // up to 64 MB bf16

    size_t used = (size_t)2 * NB * DIM * LEN * 4 + (size_t)2 * OC * DIM * 2;
    size_t perN = (size_t)OC * L2 * 2;   // 4 MB per n (bf16)
    int nchunk = 1;
    if (ws_size > used + perN) {
        size_t c = (ws_size - used) / perN;
        nchunk = (int)(c > NB ? NB : c);
    }

    hipLaunchKernelGGL(kA, dim3(DIM, NB), dim3(128), 0, stream, x, mask, w1, b1, ha, hb);
    hipLaunchKernelGGL(kW, dim3(OC * DIM / 256), dim3(256), 0, stream, w2, w2h);
    for (int base = 0; base < NB; base += nchunk) {
        int nc = nchunk < (NB - base) ? nchunk : (NB - base);
        hipLaunchKernelGGL(kB, dim3(LEN, nc), dim3(256), 0, stream, ha, hb, w2h, b2, y, base);
        hipLaunchKernelGGL(kC, dim3(OC * nc), dim3(1024), (16384 + 16 + 22) * 4, stream, y, pw, out, base);
    }
}